// Round 2
// baseline (575.616 us; speedup 1.0000x reference)
//
#include <hip/hip_runtime.h>
#include <stdint.h>

__device__ __forceinline__ float bf2f(uint32_t v) { return __uint_as_float(v << 16); }
__device__ __forceinline__ uint32_t f2bf(float f) {
  uint32_t u = __float_as_uint(f);
  return (u + 0x7fffu + ((u >> 16) & 1u)) >> 16;  // RNE
}

// jax.image.resize bilinear 16->32 closed form (edge renorm == clamp)
__device__ __forceinline__ void interp_coord(int p, int& i0, int& i1, float& f) {
  if (p == 0)       { i0 = 0;  i1 = 0;  f = 0.f; }
  else if (p == 31) { i0 = 15; i1 = 15; f = 0.f; }
  else if (p & 1)   { i0 = (p - 1) >> 1; i1 = i0 + 1; f = 0.25f; }
  else              { i0 = (p >> 1) - 1; i1 = i0 + 1; f = 0.75f; }
}

typedef short bf16x8 __attribute__((ext_vector_type(8)));
typedef float f32x4 __attribute__((ext_vector_type(4)));

// ---------------------------------------------------------------------------
// Kernel F (fused front): blocks [0,512) = weight repack (w f32 -> wr bf16
// [k][yx][o*128+i], in d_out scratch); blocks [512,4608) = two-level Haar DWT
// (x f32 -> bands bf16 [k][p][b][i]).  Independent work fused into one launch
// so the repack hides under the memory-bound DWT instead of serializing.
// LDS is the union (33.5 KB -> 4 blocks/CU; DWT needs ~10 KB/CU in flight to
// saturate HBM, so the occupancy drop is harmless).
// ---------------------------------------------------------------------------
__global__ __launch_bounds__(256) void front_kernel(const float* __restrict__ x,
                                                    const float* __restrict__ w1,
                                                    const float* __restrict__ w2,
                                                    const float* __restrict__ w3,
                                                    const float* __restrict__ w4,
                                                    uint16_t* __restrict__ bands,
                                                    uint16_t* __restrict__ wr) {
  __shared__ uint16_t sh[64 * 262];  // union: wrepack [64i][yx pad 262] / dwt [4k][32w][c pad 34]
  const int t = threadIdx.x;
  if (blockIdx.x < 512) {
    // ---- wrepack ----
    const int bid = blockIdx.x;
    const int k = bid >> 7;
    const int o = bid & 127;
    const float* src = (k == 0) ? w1 : (k == 1) ? w2 : (k == 2) ? w3 : w4;
    uint32_t* Lu = (uint32_t*)sh;
    for (int ih = 0; ih < 2; ++ih) {    // two halves of i (64 each)
      if (ih) __syncthreads();
#pragma unroll
      for (int j = 0; j < 16; ++j) {
        const int ridx = t + (j << 8);  // 0..4095
        const int il = ridx >> 6;       // 0..63 local i
        const int x4 = ridx & 63;       // float4 within 256 yx
        float4 v = *(const float4*)(src + (((size_t)((ih * 64 + il) * 128 + o)) << 8) + (x4 << 2));
        Lu[il * 131 + (x4 << 1)]     = f2bf(v.x) | (f2bf(v.y) << 16);
        Lu[il * 131 + (x4 << 1) + 1] = f2bf(v.z) | (f2bf(v.w) << 16);
      }
      __syncthreads();
#pragma unroll
      for (int j = 0; j < 32; ++j) {
        const int oidx = t + (j << 8);  // 0..8191
        const int yx = oidx >> 5;       // 0..255
        const int q  = oidx & 31;       // i-pair within this 64-i half
        const uint32_t lo = sh[(q << 1) * 262 + yx];
        const uint32_t hi = sh[((q << 1) + 1) * 262 + yx];
        uint32_t* dst = (uint32_t*)wr + (((size_t)(k << 8) + yx) << 13) + (o << 6) + (ih << 5) + q;
        *dst = lo | (hi << 16);
      }
    }
  } else {
    // ---- dwt ----
    const int bid = blockIdx.x - 512;
    const int cg4 = bid & 3;          // 32-channel group
    const int h   = (bid >> 2) & 31;  // output row
    const int b   = bid >> 7;         // batch
    const int w   = t & 31;           // output col
    const int cl  = t >> 5;           // 0..7
#pragma unroll
    for (int cc = 0; cc < 4; ++cc) {
      const int c = cl + (cc << 3);   // 0..31 local channel
      const float* xc = x + (((size_t)(b << 7) + (cg4 << 5) + c) << 14) + (h << 9) + (w << 2);
      float4 r0 = *(const float4*)(xc);
      float4 r1 = *(const float4*)(xc + 128);
      float4 r2 = *(const float4*)(xc + 256);
      float4 r3 = *(const float4*)(xc + 384);
      float S00 = r0.x + r0.y + r1.x + r1.y;
      float S01 = r0.z + r0.w + r1.z + r1.w;
      float S10 = r2.x + r2.y + r3.x + r3.y;
      float S11 = r2.z + r2.w + r3.z + r3.w;
      sh[(0 * 32 + w) * 34 + c] = (uint16_t)f2bf(0.25f * (S00 + S01 + S10 + S11));  // ll
      sh[(1 * 32 + w) * 34 + c] = (uint16_t)f2bf(0.25f * (S00 - S01 + S10 - S11));  // lh
      sh[(2 * 32 + w) * 34 + c] = (uint16_t)f2bf(0.25f * (S00 + S01 - S10 - S11));  // hl
      sh[(3 * 32 + w) * 34 + c] = (uint16_t)f2bf(0.25f * (S00 - S01 - S10 + S11));  // hh
    }
    __syncthreads();
    const uint32_t* tl = (const uint32_t*)sh;
    uint32_t* bo = (uint32_t*)bands;
#pragma unroll
    for (int j = 0; j < 8; ++j) {
      const int idx = t + (j << 8);   // 0..2047
      const int k   = idx >> 9;
      const int rem = idx & 511;
      const int w2  = rem >> 4;
      const int qq  = rem & 15;       // i-pair within 32-ch group
      const uint32_t v = tl[(k * 32 + w2) * 17 + qq];
      bo[(((size_t)(k << 10) + (h << 5) + w2) << 11) + (b << 6) + (cg4 << 4) + qq] = v;
    }
  }
}

// ---------------------------------------------------------------------------
// Kernel C: MFMA bf16 GEMM with fused bilinear weight interp.  One block per
// (k, y-group, x-group) where each group is the p-pair sharing the same
// bilinear cell window ({2a+1,2a+2} pairs, plus the f=0 edge pair {0,31}) —
// so the 4 x 32 KB wr cell reads are amortized over FOUR p's (16x less cell
// traffic than one-p-per-block).  Uniform coefficient scheme: p(i,j) uses
// wy_i x wx_j against the shared quad; edge p's get exact-zero coefficients.
// lid mapping chunks same-(k,y)-slab blocks onto one XCD for L2 reuse.
// ---------------------------------------------------------------------------
__global__ __launch_bounds__(256) void gemm_kernel(const uint16_t* __restrict__ bands,
                                                   const uint16_t* __restrict__ wr,
                                                   uint16_t* __restrict__ ws2) {
  __shared__ uint16_t Wt[128 * 136];  // [o][i pad 136], 34.8 KB -> 4 blocks/CU
  const int bid = blockIdx.x;                       // 1024
  const int lid = ((bid & 7) << 7) + (bid >> 3);    // XCD-chunked (bijective, 1024%8==0)
  const int xg = lid & 15;
  const int yg = (lid >> 4) & 15;
  const int k  = lid >> 8;
  int pys[2], pxs[2], ya, yb, xa, xb;
  if (yg < 15) { pys[0] = 2 * yg + 1; pys[1] = 2 * yg + 2; ya = yg; yb = yg + 1; }
  else         { pys[0] = 0;          pys[1] = 31;         ya = 0;  yb = 15;     }
  if (xg < 15) { pxs[0] = 2 * xg + 1; pxs[1] = 2 * xg + 2; xa = xg; xb = xg + 1; }
  else         { pxs[0] = 0;          pxs[1] = 31;         xa = 0;  xb = 15;     }
  // per-p weights against the shared cell quad
  float WY[2][2], WX[2][2];
#pragma unroll
  for (int i = 0; i < 2; ++i) {
    int y0_, y1_; float fy;
    interp_coord(pys[i], y0_, y1_, fy);
    WY[i][0] = (y0_ == ya ? (1.f - fy) : 0.f) + (y1_ == ya ? fy : 0.f);
    WY[i][1] = (y0_ == yb ? (1.f - fy) : 0.f) + (y1_ == yb ? fy : 0.f);
    int x0_, x1_; float fx;
    interp_coord(pxs[i], x0_, x1_, fx);
    WX[i][0] = (x0_ == xa ? (1.f - fx) : 0.f) + (x1_ == xa ? fx : 0.f);
    WX[i][1] = (x0_ == xb ? (1.f - fx) : 0.f) + (x1_ == xb ? fx : 0.f);
  }
  const uint16_t* wk = wr + ((size_t)k << 22);  // k * 256 * 16384
  const uint4* rA = (const uint4*)wk + (size_t)((ya << 4) + xa) * 2048;
  const uint4* rB = (const uint4*)wk + (size_t)((ya << 4) + xb) * 2048;
  const uint4* rC = (const uint4*)wk + (size_t)((yb << 4) + xa) * 2048;
  const uint4* rD = (const uint4*)wk + (size_t)((yb << 4) + xb) * 2048;
  const int t  = threadIdx.x;
  const int wv = t >> 6;
  const int l  = t & 63;
  const int lr = l & 15;           // row-in-tile
  const int lk = (l >> 4) << 3;    // k-offset within 32-chunk: 0,8,16,24
  uint32_t* Wtu = (uint32_t*)Wt;
#pragma unroll 1
  for (int pp = 0; pp < 4; ++pp) {
    const int iy = pp >> 1, ix = pp & 1;
    const float c00 = WY[iy][0] * WX[ix][0], c01 = WY[iy][0] * WX[ix][1];
    const float c10 = WY[iy][1] * WX[ix][0], c11 = WY[iy][1] * WX[ix][1];
    const int p = (pys[iy] << 5) + pxs[ix];
    if (pp) __syncthreads();  // previous epilogue's LDS reads done before rebuild
    // ---- build Wt[o][i] for this p (cells re-hit L1/L2 after first pass) ----
#pragma unroll
    for (int j = 0; j < 8; ++j) {
      const int fi = t + (j << 8);   // uint4 index 0..2047
      const int o  = fi >> 4;
      const int i8 = fi & 15;        // x8 elems
      const uint4 a = rA[fi], b = rB[fi], c = rC[fi], d = rD[fi];
      uint32_t ou[4];
#pragma unroll
      for (int cc = 0; cc < 4; ++cc) {
        const uint32_t ua = (&a.x)[cc], ub = (&b.x)[cc], uc = (&c.x)[cc], ud = (&d.x)[cc];
        float lo = c00 * __uint_as_float(ua << 16) + c01 * __uint_as_float(ub << 16)
                 + c10 * __uint_as_float(uc << 16) + c11 * __uint_as_float(ud << 16);
        float hi = c00 * __uint_as_float(ua & 0xffff0000u) + c01 * __uint_as_float(ub & 0xffff0000u)
                 + c10 * __uint_as_float(uc & 0xffff0000u) + c11 * __uint_as_float(ud & 0xffff0000u);
        ou[cc] = f2bf(lo) | (f2bf(hi) << 16);
      }
      *(uint4*)(Wtu + o * 68 + (i8 << 2)) = make_uint4(ou[0], ou[1], ou[2], ou[3]);
    }
    __syncthreads();
    // ---- MFMA 32(b) x 128(o) x 128(i); wave wv owns o in [32wv, 32wv+32) ----
    const uint16_t* gA = bands + (((size_t)(k << 10) + p) << 12);
    bf16x8 af[2][4], bg[2][4];
#pragma unroll
    for (int s = 0; s < 4; ++s) {
#pragma unroll
      for (int m = 0; m < 2; ++m)
        af[m][s] = *(const bf16x8*)(gA + (((m << 4) + lr) << 7) + (s << 5) + lk);
#pragma unroll
      for (int n = 0; n < 2; ++n)
        bg[n][s] = *(const bf16x8*)(&Wt[((wv << 5) + (n << 4) + lr) * 136 + (s << 5) + lk]);
    }
    f32x4 acc[2][2] = {};
#pragma unroll
    for (int s = 0; s < 4; ++s)
#pragma unroll
      for (int m = 0; m < 2; ++m)
#pragma unroll
        for (int n = 0; n < 2; ++n)
          acc[m][n] = __builtin_amdgcn_mfma_f32_16x16x32_bf16(af[m][s], bg[n][s], acc[m][n], 0, 0, 0);
    __syncthreads();
    // ---- D -> LDS (reuse Wt as Ds[32][136]) -> coalesced global ----
    uint16_t* Ds = Wt;
#pragma unroll
    for (int m = 0; m < 2; ++m)
#pragma unroll
      for (int n = 0; n < 2; ++n)
#pragma unroll
        for (int r = 0; r < 4; ++r) {
          const int b_ = (m << 4) + ((l >> 4) << 2) + r;          // batch row
          const int o_ = (wv << 5) + (n << 4) + lr;               // out channel
          Ds[b_ * 136 + o_] = (uint16_t)f2bf(acc[m][n][r]);
        }
    __syncthreads();
    uint32_t* outp = (uint32_t*)(ws2 + (((size_t)(k << 10) + p) << 12));
    const uint32_t* Dsu = (const uint32_t*)Ds;
#pragma unroll
    for (int j = 0; j < 8; ++j) {
      const int idx = t + (j << 8);   // 0..2047 u32
      const int b_ = idx >> 6, c_ = idx & 63;
      outp[idx] = Dsu[b_ * 68 + c_];
    }
  }
}

// ---------------------------------------------------------------------------
// Kernel D: fused idwt + zero-band 2x upsample.  (unchanged — stream floor)
// ---------------------------------------------------------------------------
__global__ __launch_bounds__(256) void idwt_kernel(const uint16_t* __restrict__ ws2,
                                                   float* __restrict__ out) {
  __shared__ uint16_t Ls[4 * 32 * 130];  // [k][w][o pad 130], 33.3 KB
  const int bid = blockIdx.x;
  const int b = bid >> 5;
  const int h = bid & 31;
  const int t = threadIdx.x;
  const uint32_t* su = (const uint32_t*)ws2;
  uint32_t* Lu = (uint32_t*)Ls;
#pragma unroll 4
  for (int j = 0; j < 32; ++j) {
    const int idx = t + (j << 8);   // 0..8191
    const int kw = idx >> 6;        // k*32+w
    const int uo = idx & 63;
    const int k = kw >> 5, w = kw & 31;
    const uint32_t v = su[(((size_t)(k << 10) + (h << 5) + w) << 11) + (b << 6) + uo];
    Lu[kw * 65 + uo] = v;
  }
  __syncthreads();
  const int x4 = t & 31;   // w, and the out float4 index
  const int og = t >> 5;
  for (int pp = 0; pp < 16; ++pp) {
    const int o = (pp << 3) + og;
    const float A = bf2f(Ls[(0 * 32 + x4) * 130 + o]);
    const float B = bf2f(Ls[(1 * 32 + x4) * 130 + o]);
    const float C = bf2f(Ls[(2 * 32 + x4) * 130 + o]);
    const float D = bf2f(Ls[(3 * 32 + x4) * 130 + o]);
    const float E = A + B, F = A - B, G = C + D, Hh = C - D;
    const float vL0 = 0.25f * (E + G),  vR0 = 0.25f * (F + Hh);  // rows 0,1
    const float vL1 = 0.25f * (E - G),  vR1 = 0.25f * (F - Hh);  // rows 2,3
    float* ob = out + (((size_t)(b << 7) + o) << 14) + (h << 9) + (x4 << 2);
    float4 top = make_float4(vL0, vL0, vR0, vR0);
    float4 bot = make_float4(vL1, vL1, vR1, vR1);
    *(float4*)(ob)       = top;
    *(float4*)(ob + 128) = top;
    *(float4*)(ob + 256) = bot;
    *(float4*)(ob + 384) = bot;
  }
}

extern "C" void kernel_launch(void* const* d_in, const int* in_sizes, int n_in,
                              void* d_out, int out_size, void* d_ws, size_t ws_size,
                              hipStream_t stream) {
  const float* x  = (const float*)d_in[0];
  const float* w1 = (const float*)d_in[1];
  const float* w2 = (const float*)d_in[2];
  const float* w3 = (const float*)d_in[3];
  const float* w4 = (const float*)d_in[4];

  uint16_t* bands = (uint16_t*)d_ws;            // 4*1024*4096 bf16 = 33.5 MB
  uint16_t* ws2   = bands + (size_t)16777216;   // 4*1024*4096 bf16 = 33.5 MB
  // wr (33.5 MB bf16 repacked weights) lives in d_out as scratch; idwt_kernel
  // rewrites all of d_out afterwards (stream-ordered, no overlap with reads).
  uint16_t* wr = (uint16_t*)d_out;

  front_kernel<<<4608, 256, 0, stream>>>(x, w1, w2, w3, w4, bands, wr);
  gemm_kernel<<<1024, 256, 0, stream>>>(bands, wr, ws2);
  idwt_kernel<<<1024, 256, 0, stream>>>(ws2, (float*)d_out);
}

// Round 3
// 563.117 us; speedup vs baseline: 1.0222x; 1.0222x over previous
//
#include <hip/hip_runtime.h>
#include <stdint.h>

__device__ __forceinline__ float bf2f(uint32_t v) { return __uint_as_float(v << 16); }
__device__ __forceinline__ uint32_t f2bf(float f) {
  uint32_t u = __float_as_uint(f);
  return (u + 0x7fffu + ((u >> 16) & 1u)) >> 16;  // RNE
}

// jax.image.resize bilinear 16->32 closed form (edge renorm == clamp)
__device__ __forceinline__ void interp_coord(int p, int& i0, int& i1, float& f) {
  if (p == 0)       { i0 = 0;  i1 = 0;  f = 0.f; }
  else if (p == 31) { i0 = 15; i1 = 15; f = 0.f; }
  else if (p & 1)   { i0 = (p - 1) >> 1; i1 = i0 + 1; f = 0.25f; }
  else              { i0 = (p >> 1) - 1; i1 = i0 + 1; f = 0.75f; }
}

typedef short bf16x8 __attribute__((ext_vector_type(8)));
typedef float f32x4 __attribute__((ext_vector_type(4)));

// ---------------------------------------------------------------------------
// Kernel F (fused front): blocks [0,512) = weight repack (w f32 -> wr bf16
// [k][yx][o*128+i], in d_out scratch); blocks [512,4608) = two-level Haar DWT
// (x f32 -> bands bf16 [k][p][b][i]).  The repack hides under the
// memory-bound DWT instead of serializing.  LDS union = 16.5 KB (wrepack in
// 32-i chunks) so the fused kernel keeps the wave-limited 8 blocks/CU the
// DWT needs for latency hiding (R2's 33.5 KB union halved it — regression).
// ---------------------------------------------------------------------------
__global__ __launch_bounds__(256) void front_kernel(const float* __restrict__ x,
                                                    const float* __restrict__ w1,
                                                    const float* __restrict__ w2,
                                                    const float* __restrict__ w3,
                                                    const float* __restrict__ w4,
                                                    uint16_t* __restrict__ bands,
                                                    uint16_t* __restrict__ wr) {
  __shared__ uint16_t sh[32 * 258];  // union: wrepack [32i][yx pad 258] (16.5KB) / dwt [4k][32w][c pad 34] (8.7KB)
  const int t = threadIdx.x;
  if (blockIdx.x < 512) {
    // ---- wrepack: 4 chunks of 32 i ----
    const int bid = blockIdx.x;
    const int k = bid >> 7;
    const int o = bid & 127;
    const float* src = (k == 0) ? w1 : (k == 1) ? w2 : (k == 2) ? w3 : w4;
    uint32_t* Lu = (uint32_t*)sh;    // row stride 129 u32 (odd)
    for (int ic = 0; ic < 4; ++ic) {
      if (ic) __syncthreads();
#pragma unroll
      for (int j = 0; j < 8; ++j) {
        const int ridx = t + (j << 8);  // 0..2047
        const int il = ridx >> 6;       // 0..31 local i
        const int x4 = ridx & 63;       // float4 within 256 yx
        float4 v = *(const float4*)(src + (((size_t)(((ic << 5) + il) * 128 + o)) << 8) + (x4 << 2));
        Lu[il * 129 + (x4 << 1)]     = f2bf(v.x) | (f2bf(v.y) << 16);
        Lu[il * 129 + (x4 << 1) + 1] = f2bf(v.z) | (f2bf(v.w) << 16);
      }
      __syncthreads();
      // emit: 16 i-pairs x 256 yx -> 64B coalesced runs
#pragma unroll
      for (int j = 0; j < 16; ++j) {
        const int oidx = t + (j << 8);  // 0..4095
        const int yx = oidx >> 4;       // 0..255
        const int q  = oidx & 15;       // i-pair within this 32-i chunk
        const uint32_t lo = sh[(q << 1) * 258 + yx];
        const uint32_t hi = sh[((q << 1) + 1) * 258 + yx];
        uint32_t* dst = (uint32_t*)wr + (((size_t)(k << 8) + yx) << 13) + (o << 6) + (ic << 4) + q;
        *dst = lo | (hi << 16);
      }
    }
  } else {
    // ---- dwt ----
    const int bid = blockIdx.x - 512;
    const int cg4 = bid & 3;          // 32-channel group
    const int h   = (bid >> 2) & 31;  // output row
    const int b   = bid >> 7;         // batch
    const int w   = t & 31;           // output col
    const int cl  = t >> 5;           // 0..7
#pragma unroll
    for (int cc = 0; cc < 4; ++cc) {
      const int c = cl + (cc << 3);   // 0..31 local channel
      const float* xc = x + (((size_t)(b << 7) + (cg4 << 5) + c) << 14) + (h << 9) + (w << 2);
      float4 r0 = *(const float4*)(xc);
      float4 r1 = *(const float4*)(xc + 128);
      float4 r2 = *(const float4*)(xc + 256);
      float4 r3 = *(const float4*)(xc + 384);
      float S00 = r0.x + r0.y + r1.x + r1.y;
      float S01 = r0.z + r0.w + r1.z + r1.w;
      float S10 = r2.x + r2.y + r3.x + r3.y;
      float S11 = r2.z + r2.w + r3.z + r3.w;
      sh[(0 * 32 + w) * 34 + c] = (uint16_t)f2bf(0.25f * (S00 + S01 + S10 + S11));  // ll
      sh[(1 * 32 + w) * 34 + c] = (uint16_t)f2bf(0.25f * (S00 - S01 + S10 - S11));  // lh
      sh[(2 * 32 + w) * 34 + c] = (uint16_t)f2bf(0.25f * (S00 + S01 - S10 - S11));  // hl
      sh[(3 * 32 + w) * 34 + c] = (uint16_t)f2bf(0.25f * (S00 - S01 - S10 + S11));  // hh
    }
    __syncthreads();
    const uint32_t* tl = (const uint32_t*)sh;
    uint32_t* bo = (uint32_t*)bands;
#pragma unroll
    for (int j = 0; j < 8; ++j) {
      const int idx = t + (j << 8);   // 0..2047
      const int k   = idx >> 9;
      const int rem = idx & 511;
      const int w2  = rem >> 4;
      const int qq  = rem & 15;       // i-pair within 32-ch group
      const uint32_t v = tl[(k * 32 + w2) * 17 + qq];
      bo[(((size_t)(k << 10) + (h << 5) + w2) << 11) + (b << 6) + (cg4 << 4) + qq] = v;
    }
  }
}

// ---------------------------------------------------------------------------
// Kernel C: per (p,k) 32x128x128 GEMM via MFMA bf16, with fused bilinear
// weight interpolation (R1 version, verbatim).  Natural dispatch order gives
// each XCD a constant-k row-walk (p += 2) whose 4-cell window is L2-resident
// — do not swizzle, do not group p's (R2 regression).
// ---------------------------------------------------------------------------
__global__ __launch_bounds__(256) void gemm_kernel(const uint16_t* __restrict__ bands,
                                                   const uint16_t* __restrict__ wr,
                                                   uint16_t* __restrict__ ws2) {
  __shared__ uint16_t Wt[128 * 136];  // [o][i pad 136], 34.8 KB -> 4 blocks/CU
  const int bid = blockIdx.x;
  const int k = bid & 3;
  const int p = bid >> 2;
  const int t = threadIdx.x;
  // ---- fused interp: build Wt[o][i] ----
  const int py = p >> 5, px = p & 31;
  int y0, y1, x0, x1; float fy, fx;
  interp_coord(py, y0, y1, fy);
  interp_coord(px, x0, x1, fx);
  const float c00 = (1.f - fy) * (1.f - fx), c01 = (1.f - fy) * fx;
  const float c10 = fy * (1.f - fx),         c11 = fy * fx;
  const uint16_t* wk = wr + ((size_t)k << 22);  // k * 256 * 16384
  const uint4* rA = (const uint4*)(wk + (((size_t)(y0 << 4) + x0) << 14));
  const uint4* rB = (const uint4*)(wk + (((size_t)(y0 << 4) + x1) << 14));
  const uint4* rC = (const uint4*)(wk + (((size_t)(y1 << 4) + x0) << 14));
  const uint4* rD = (const uint4*)(wk + (((size_t)(y1 << 4) + x1) << 14));
  uint32_t* Wtu = (uint32_t*)Wt;
#pragma unroll
  for (int j = 0; j < 8; ++j) {
    const int fi = t + (j << 8);   // uint4 index 0..2047
    const int o  = fi >> 4;
    const int i8 = fi & 15;        // x8 elems
    const uint4 a = rA[fi], b = rB[fi], c = rC[fi], d = rD[fi];
    uint32_t ou[4];
#pragma unroll
    for (int cc = 0; cc < 4; ++cc) {
      const uint32_t ua = (&a.x)[cc], ub = (&b.x)[cc], uc = (&c.x)[cc], ud = (&d.x)[cc];
      float lo = c00 * __uint_as_float(ua << 16) + c01 * __uint_as_float(ub << 16)
               + c10 * __uint_as_float(uc << 16) + c11 * __uint_as_float(ud << 16);
      float hi = c00 * __uint_as_float(ua & 0xffff0000u) + c01 * __uint_as_float(ub & 0xffff0000u)
               + c10 * __uint_as_float(uc & 0xffff0000u) + c11 * __uint_as_float(ud & 0xffff0000u);
      ou[cc] = f2bf(lo) | (f2bf(hi) << 16);
    }
    *(uint4*)(Wtu + o * 68 + (i8 << 2)) = make_uint4(ou[0], ou[1], ou[2], ou[3]);
  }
  __syncthreads();
  // ---- MFMA 32(b) x 128(o) x 128(i); wave wv owns o in [32wv, 32wv+32) ----
  const int wv = t >> 6;
  const int l  = t & 63;
  const int lr = l & 15;           // row-in-tile
  const int lk = (l >> 4) << 3;    // k-offset within 32-chunk: 0,8,16,24
  const uint16_t* gA = bands + (((size_t)(k << 10) + p) << 12);
  bf16x8 af[2][4], bg[2][4];
#pragma unroll
  for (int s = 0; s < 4; ++s) {
#pragma unroll
    for (int m = 0; m < 2; ++m)
      af[m][s] = *(const bf16x8*)(gA + (((m << 4) + lr) << 7) + (s << 5) + lk);
#pragma unroll
    for (int n = 0; n < 2; ++n)
      bg[n][s] = *(const bf16x8*)(&Wt[((wv << 5) + (n << 4) + lr) * 136 + (s << 5) + lk]);
  }
  f32x4 acc[2][2] = {};
#pragma unroll
  for (int s = 0; s < 4; ++s)
#pragma unroll
    for (int m = 0; m < 2; ++m)
#pragma unroll
      for (int n = 0; n < 2; ++n)
        acc[m][n] = __builtin_amdgcn_mfma_f32_16x16x32_bf16(af[m][s], bg[n][s], acc[m][n], 0, 0, 0);
  __syncthreads();
  // ---- D -> LDS (reuse Wt as Ds[32][136]) -> coalesced global ----
  uint16_t* Ds = Wt;
#pragma unroll
  for (int m = 0; m < 2; ++m)
#pragma unroll
    for (int n = 0; n < 2; ++n)
#pragma unroll
      for (int r = 0; r < 4; ++r) {
        const int b_ = (m << 4) + ((l >> 4) << 2) + r;          // batch row
        const int o_ = (wv << 5) + (n << 4) + lr;               // out channel
        Ds[b_ * 136 + o_] = (uint16_t)f2bf(acc[m][n][r]);
      }
  __syncthreads();
  uint32_t* outp = (uint32_t*)(ws2 + (((size_t)(k << 10) + p) << 12));
  const uint32_t* Dsu = (const uint32_t*)Ds;
#pragma unroll
  for (int j = 0; j < 8; ++j) {
    const int idx = t + (j << 8);   // 0..2047 u32
    const int b_ = idx >> 6, c_ = idx & 63;
    outp[idx] = Dsu[b_ * 68 + c_];
  }
}

// ---------------------------------------------------------------------------
// Kernel D: fused idwt + zero-band 2x upsample.  (unchanged — stream floor)
// ---------------------------------------------------------------------------
__global__ __launch_bounds__(256) void idwt_kernel(const uint16_t* __restrict__ ws2,
                                                   float* __restrict__ out) {
  __shared__ uint16_t Ls[4 * 32 * 130];  // [k][w][o pad 130], 33.3 KB
  const int bid = blockIdx.x;
  const int b = bid >> 5;
  const int h = bid & 31;
  const int t = threadIdx.x;
  const uint32_t* su = (const uint32_t*)ws2;
  uint32_t* Lu = (uint32_t*)Ls;
#pragma unroll 4
  for (int j = 0; j < 32; ++j) {
    const int idx = t + (j << 8);   // 0..8191
    const int kw = idx >> 6;        // k*32+w
    const int uo = idx & 63;
    const int k = kw >> 5, w = kw & 31;
    const uint32_t v = su[(((size_t)(k << 10) + (h << 5) + w) << 11) + (b << 6) + uo];
    Lu[kw * 65 + uo] = v;
  }
  __syncthreads();
  const int x4 = t & 31;   // w, and the out float4 index
  const int og = t >> 5;
  for (int pp = 0; pp < 16; ++pp) {
    const int o = (pp << 3) + og;
    const float A = bf2f(Ls[(0 * 32 + x4) * 130 + o]);
    const float B = bf2f(Ls[(1 * 32 + x4) * 130 + o]);
    const float C = bf2f(Ls[(2 * 32 + x4) * 130 + o]);
    const float D = bf2f(Ls[(3 * 32 + x4) * 130 + o]);
    const float E = A + B, F = A - B, G = C + D, Hh = C - D;
    const float vL0 = 0.25f * (E + G),  vR0 = 0.25f * (F + Hh);  // rows 0,1
    const float vL1 = 0.25f * (E - G),  vR1 = 0.25f * (F - Hh);  // rows 2,3
    float* ob = out + (((size_t)(b << 7) + o) << 14) + (h << 9) + (x4 << 2);
    float4 top = make_float4(vL0, vL0, vR0, vR0);
    float4 bot = make_float4(vL1, vL1, vR1, vR1);
    *(float4*)(ob)       = top;
    *(float4*)(ob + 128) = top;
    *(float4*)(ob + 256) = bot;
    *(float4*)(ob + 384) = bot;
  }
}

extern "C" void kernel_launch(void* const* d_in, const int* in_sizes, int n_in,
                              void* d_out, int out_size, void* d_ws, size_t ws_size,
                              hipStream_t stream) {
  const float* x  = (const float*)d_in[0];
  const float* w1 = (const float*)d_in[1];
  const float* w2 = (const float*)d_in[2];
  const float* w3 = (const float*)d_in[3];
  const float* w4 = (const float*)d_in[4];

  uint16_t* bands = (uint16_t*)d_ws;            // 4*1024*4096 bf16 = 33.5 MB
  uint16_t* ws2   = bands + (size_t)16777216;   // 4*1024*4096 bf16 = 33.5 MB
  // wr (33.5 MB bf16 repacked weights) lives in d_out as scratch; idwt_kernel
  // rewrites all of d_out afterwards (stream-ordered, no overlap with reads).
  uint16_t* wr = (uint16_t*)d_out;

  front_kernel<<<4608, 256, 0, stream>>>(x, w1, w2, w3, w4, bands, wr);
  gemm_kernel<<<4096, 256, 0, stream>>>(bands, wr, ws2);
  idwt_kernel<<<1024, 256, 0, stream>>>(ws2, (float*)d_out);
}